// Round 8
// baseline (58.547 us; speedup 1.0000x reference)
//
#include <hip/hip_runtime.h>
#include <math.h>

#define BB 64
#define TT 2048
#define QD 1024
#define AD 256

__device__ __forceinline__ float tanh_fast(float x) {
    // exact algebra: tanh(x) = 1 - 2/(e^{2x}+1); __expf/__fdividef are few-ulp
    float e = __expf(2.0f * x);
    return 1.0f - __fdividef(2.0f, e + 1.0f);
}

// pq[b][a] = sum_q query[b][q] * Wq[a][q]
// one wave per (4 b's x 4 a's) tile: q rows live in registers, Wq read once
// per 4 b's -> L2 traffic ~32MB instead of ~144MB.
__global__ __launch_bounds__(256) void pq_kernel(const float* __restrict__ query,
                                                 const float* __restrict__ Wq,
                                                 float* __restrict__ pq) {
    int wg   = (blockIdx.x * blockDim.x + threadIdx.x) >> 6;  // 0..1023
    int lane = threadIdx.x & 63;
    int b0 = (wg >> 6) * 4;   // 16 b-groups
    int a0 = (wg & 63) * 4;   // 64 a-groups
    float4 qr[4][4];
    #pragma unroll
    for (int i = 0; i < 4; ++i) {
        const float4* qrow = (const float4*)(query + (size_t)(b0 + i) * QD);
        #pragma unroll
        for (int k = 0; k < 4; ++k) qr[i][k] = qrow[lane + k * 64];
    }
    float acc[4][4];
    #pragma unroll
    for (int j = 0; j < 4; ++j) {
        const float4* wrow = (const float4*)(Wq + (size_t)(a0 + j) * QD);
        float4 w4[4];
        #pragma unroll
        for (int k = 0; k < 4; ++k) w4[k] = wrow[lane + k * 64];
        #pragma unroll
        for (int i = 0; i < 4; ++i) {
            float a = 0.f;
            #pragma unroll
            for (int k = 0; k < 4; ++k)
                a += qr[i][k].x * w4[k].x + qr[i][k].y * w4[k].y
                   + qr[i][k].z * w4[k].z + qr[i][k].w * w4[k].w;
            acc[i][j] = a;
        }
    }
    #pragma unroll
    for (int off = 32; off > 0; off >>= 1)
        #pragma unroll
        for (int i = 0; i < 4; ++i)
            #pragma unroll
            for (int j = 0; j < 4; ++j)
                acc[i][j] += __shfl_down(acc[i][j], off, 64);
    if (lane == 0) {
        #pragma unroll
        for (int i = 0; i < 4; ++i) {
            float4 r = make_float4(acc[i][0], acc[i][1], acc[i][2], acc[i][3]);
            ((float4*)(pq + (size_t)(b0 + i) * AD))[a0 >> 2] = r;
        }
    }
}

// For each row (b,t): exp( mask * sum_a tanh(pq[b][a]+esp[b][t][a]) * v[a] )
// R1/R2 best-measured shape: 4 rows/wave, 8192 fresh blocks, straight-line
// body. IDEMPOTENT (pure function of inputs) -> safe to launch twice; this
// round launches it twice to measure the L3-warm energy-pass cost directly.
__global__ __launch_bounds__(256) void energy_kernel(const float* __restrict__ esp,
                                                     const float* __restrict__ pq,
                                                     const float* __restrict__ v,
                                                     const int* __restrict__ chars,
                                                     float* __restrict__ expout,
                                                     float* __restrict__ partials) {
    __shared__ float red[4];
    int wave = threadIdx.x >> 6;
    int lane = threadIdx.x & 63;
    int wg   = blockIdx.x * 4 + wave;
    int w0 = wg * 4;          // first row (b*T + t), 4-aligned -> same b
    int b  = w0 >> 11;        // / TT
    const float4* erow = (const float4*)(esp + (size_t)w0 * AD);
    float4 e4[4];
    #pragma unroll
    for (int j = 0; j < 4; ++j) e4[j] = erow[j * 64 + lane];
    float4 p4 = ((const float4*)(pq + (size_t)b * AD))[lane];
    float4 v4 = ((const float4*)v)[lane];
    float s[4];
    #pragma unroll
    for (int j = 0; j < 4; ++j) {
        s[j] = tanh_fast(p4.x + e4[j].x) * v4.x
             + tanh_fast(p4.y + e4[j].y) * v4.y
             + tanh_fast(p4.z + e4[j].z) * v4.z
             + tanh_fast(p4.w + e4[j].w) * v4.w;
    }
    #pragma unroll
    for (int off = 32; off > 0; off >>= 1)
        #pragma unroll
        for (int j = 0; j < 4; ++j)
            s[j] += __shfl_down(s[j], off, 64);
    if (lane == 0) {
        int4 cc = *(const int4*)(chars + w0);
        float4 r;
        r.x = cc.x ? __expf(s[0]) : 1.0f;   // masked energy = 0 -> exp = 1
        r.y = cc.y ? __expf(s[1]) : 1.0f;
        r.z = cc.z ? __expf(s[2]) : 1.0f;
        r.w = cc.w ? __expf(s[3]) : 1.0f;
        *(float4*)(expout + w0) = r;
        red[wave] = r.x + r.y + r.z + r.w;
    }
    __syncthreads();
    if (threadIdx.x == 0)
        partials[blockIdx.x] = red[0] + red[1] + red[2] + red[3];
}

// one block per b: reduce the 128 block-partials, scale the 2048 exp values
__global__ __launch_bounds__(1024) void normalize_kernel(float* __restrict__ io,
                                                         const float* __restrict__ partials) {
    __shared__ float red[16];
    int tid  = threadIdx.x;
    int wave = tid >> 6, lane = tid & 63;
    int b = blockIdx.x;
    float p = (tid < 128) ? partials[b * 128 + tid] : 0.0f;
    #pragma unroll
    for (int off = 32; off > 0; off >>= 1)
        p += __shfl_xor(p, off, 64);
    if (lane == 0) red[wave] = p;
    __syncthreads();
    float s = 0.f;
    #pragma unroll
    for (int i = 0; i < 16; ++i) s += red[i];
    float inv = __fdividef(1.0f, s);
    float2* row = (float2*)(io + (size_t)b * TT);
    float2 vv = row[tid];
    row[tid] = make_float2(vv.x * inv, vv.y * inv);
}

extern "C" void kernel_launch(void* const* d_in, const int* in_sizes, int n_in,
                              void* d_out, int out_size, void* d_ws, size_t ws_size,
                              hipStream_t stream) {
    const float* esp   = (const float*)d_in[0];  // (B,T,AD)
    const float* query = (const float*)d_in[1];  // (B,QD)
    const int*   chars = (const int*)d_in[2];    // (B,T)
    // d_in[3] = t (unused by the reference math)
    const float* Wq    = (const float*)d_in[4];  // (AD,QD)
    const float* v     = (const float*)d_in[5];  // (AD,)
    float* out = (float*)d_out;                  // (B,T)
    float* pq       = (float*)d_ws;                    // B*AD floats
    float* partials = (float*)d_ws + BB * AD;          // 8192 floats

    pq_kernel<<<256, 256, 0, stream>>>(query, Wq, pq);
    // MEASUREMENT: energy launched twice (idempotent). dur_us minus the R2
    // baseline (35.5us) ~= cost of an L3-warm energy pass.
    energy_kernel<<<(BB * TT) / 16, 256, 0, stream>>>(esp, pq, v, chars, out, partials);
    energy_kernel<<<(BB * TT) / 16, 256, 0, stream>>>(esp, pq, v, chars, out, partials);
    normalize_kernel<<<BB, 1024, 0, stream>>>(out, partials);
}

// Round 9
// 34.920 us; speedup vs baseline: 1.6766x; 1.6766x over previous
//
#include <hip/hip_runtime.h>
#include <math.h>

#define BB 64
#define TT 2048
#define QD 1024
#define AD 256

__device__ __forceinline__ float tanh_fast(float x) {
    // exact algebra: tanh(x) = 1 - 2/(e^{2x}+1); __expf/__fdividef are few-ulp
    float e = __expf(2.0f * x);
    return 1.0f - __fdividef(2.0f, e + 1.0f);
}

// pq[b][a] = sum_q query[b][q] * Wq[a][q]
// one wave per (4 b's x 4 a's) tile: q rows live in registers, Wq read once
// per 4 b's -> L2 traffic ~32MB instead of ~144MB.
__global__ __launch_bounds__(256) void pq_kernel(const float* __restrict__ query,
                                                 const float* __restrict__ Wq,
                                                 float* __restrict__ pq) {
    int wg   = (blockIdx.x * blockDim.x + threadIdx.x) >> 6;  // 0..1023
    int lane = threadIdx.x & 63;
    int b0 = (wg >> 6) * 4;   // 16 b-groups
    int a0 = (wg & 63) * 4;   // 64 a-groups
    float4 qr[4][4];
    #pragma unroll
    for (int i = 0; i < 4; ++i) {
        const float4* qrow = (const float4*)(query + (size_t)(b0 + i) * QD);
        #pragma unroll
        for (int k = 0; k < 4; ++k) qr[i][k] = qrow[lane + k * 64];
    }
    float acc[4][4];
    #pragma unroll
    for (int j = 0; j < 4; ++j) {
        const float4* wrow = (const float4*)(Wq + (size_t)(a0 + j) * QD);
        float4 w4[4];
        #pragma unroll
        for (int k = 0; k < 4; ++k) w4[k] = wrow[lane + k * 64];
        #pragma unroll
        for (int i = 0; i < 4; ++i) {
            float a = 0.f;
            #pragma unroll
            for (int k = 0; k < 4; ++k)
                a += qr[i][k].x * w4[k].x + qr[i][k].y * w4[k].y
                   + qr[i][k].z * w4[k].z + qr[i][k].w * w4[k].w;
            acc[i][j] = a;
        }
    }
    #pragma unroll
    for (int off = 32; off > 0; off >>= 1)
        #pragma unroll
        for (int i = 0; i < 4; ++i)
            #pragma unroll
            for (int j = 0; j < 4; ++j)
                acc[i][j] += __shfl_down(acc[i][j], off, 64);
    if (lane == 0) {
        #pragma unroll
        for (int i = 0; i < 4; ++i) {
            float4 r = make_float4(acc[i][0], acc[i][1], acc[i][2], acc[i][3]);
            ((float4*)(pq + (size_t)(b0 + i) * AD))[a0 >> 2] = r;
        }
    }
}

// energies[b][t] = mask * sum_a tanh(pq[b][a] + esp[b][t][a]) * v[a]
// one wave per 4 consecutive rows (same b): 4 loads in flight, 4 interleaved
// reduction chains, float4 store. Measured-best shape (R1 = 34.8us); every
// structural deviation (persistence, 8-row fold, nt loads, fused exp+barrier,
// threadfence fusion) regressed.
__global__ __launch_bounds__(256) void energy_kernel(const float* __restrict__ esp,
                                                     const float* __restrict__ pq,
                                                     const float* __restrict__ v,
                                                     const int* __restrict__ chars,
                                                     float* __restrict__ energies) {
    int wg   = (blockIdx.x * blockDim.x + threadIdx.x) >> 6;
    int lane = threadIdx.x & 63;
    int w0 = wg * 4;          // first row (b*T + t), 4-aligned -> same b
    int b  = w0 >> 11;        // / TT
    const float4* erow = (const float4*)(esp + (size_t)w0 * AD);
    float4 e4[4];
    #pragma unroll
    for (int j = 0; j < 4; ++j) e4[j] = erow[j * 64 + lane];
    float4 p4 = ((const float4*)(pq + (size_t)b * AD))[lane];
    float4 v4 = ((const float4*)v)[lane];
    float s[4];
    #pragma unroll
    for (int j = 0; j < 4; ++j) {
        s[j] = tanh_fast(p4.x + e4[j].x) * v4.x
             + tanh_fast(p4.y + e4[j].y) * v4.y
             + tanh_fast(p4.z + e4[j].z) * v4.z
             + tanh_fast(p4.w + e4[j].w) * v4.w;
    }
    #pragma unroll
    for (int off = 32; off > 0; off >>= 1)
        #pragma unroll
        for (int j = 0; j < 4; ++j)
            s[j] += __shfl_down(s[j], off, 64);
    if (lane == 0) {
        int4 cc = *(const int4*)(chars + w0);
        float4 r;
        r.x = cc.x ? s[0] : 0.f;
        r.y = cc.y ? s[1] : 0.f;
        r.z = cc.z ? s[2] : 0.f;
        r.w = cc.w ? s[3] : 0.f;
        *(float4*)(energies + w0) = r;
    }
}

// in-place masked softmax over each row of length T; one block (1024 thr) per b
__global__ __launch_bounds__(1024) void softmax_kernel(float* __restrict__ io) {
    __shared__ float red[16];
    int tid  = threadIdx.x;
    int wave = tid >> 6, lane = tid & 63;
    float* row = io + (size_t)blockIdx.x * TT;
    float2 vv = ((float2*)row)[tid];
    float m = fmaxf(vv.x, vv.y);
    #pragma unroll
    for (int off = 32; off > 0; off >>= 1)
        m = fmaxf(m, __shfl_xor(m, off, 64));
    if (lane == 0) red[wave] = m;
    __syncthreads();
    float mm = red[0];
    #pragma unroll
    for (int i = 1; i < 16; ++i) mm = fmaxf(mm, red[i]);
    __syncthreads();
    float e0 = __expf(vv.x - mm);
    float e1 = __expf(vv.y - mm);
    float s = e0 + e1;
    #pragma unroll
    for (int off = 32; off > 0; off >>= 1)
        s += __shfl_xor(s, off, 64);
    if (lane == 0) red[wave] = s;
    __syncthreads();
    float ss = 0.f;
    #pragma unroll
    for (int i = 0; i < 16; ++i) ss += red[i];
    float inv = __fdividef(1.0f, ss);
    ((float2*)row)[tid] = make_float2(e0 * inv, e1 * inv);
}

extern "C" void kernel_launch(void* const* d_in, const int* in_sizes, int n_in,
                              void* d_out, int out_size, void* d_ws, size_t ws_size,
                              hipStream_t stream) {
    const float* esp   = (const float*)d_in[0];  // (B,T,AD)
    const float* query = (const float*)d_in[1];  // (B,QD)
    const int*   chars = (const int*)d_in[2];    // (B,T)
    // d_in[3] = t (unused by the reference math)
    const float* Wq    = (const float*)d_in[4];  // (AD,QD)
    const float* v     = (const float*)d_in[5];  // (AD,)
    float* out = (float*)d_out;                  // (B,T)
    float* pq  = (float*)d_ws;                   // B*AD floats = 64KB scratch

    pq_kernel<<<256, 256, 0, stream>>>(query, Wq, pq);
    energy_kernel<<<(BB * TT) / 16, 256, 0, stream>>>(esp, pq, v, chars, out);
    softmax_kernel<<<BB, 1024, 0, stream>>>(out);
}